// Round 6
// baseline (272.893 us; speedup 1.0000x reference)
//
#include <hip/hip_runtime.h>
#include <hip/hip_bf16.h>
#include <cstdint>
#include <cstddef>

typedef __attribute__((ext_vector_type(8))) short bf16x8;
typedef __attribute__((ext_vector_type(4))) float f32x4;

static constexpr int CB  = 2;
static constexpr int CS  = 2048;
static constexpr int CH  = 2048;
static constexpr int CNH = 32;
static constexpr int CNKV = 8;
static constexpr int CHD = 64;
static constexpr int CTHD = 3072; // (NH + 2*NKV)*HD

__device__ __forceinline__ void gload_lds16(const void* g, void* l) {
  __builtin_amdgcn_global_load_lds(
      (const __attribute__((address_space(1))) unsigned int*)g,
      (__attribute__((address_space(3))) unsigned int*)l, 16, 0, 0);
}

__device__ __forceinline__ unsigned short bfbits(float f) {
  __hip_bfloat16 h = __float2bfloat16(f);
  return *(unsigned short*)&h;
}

// ---------------- elementwise fp32 -> bf16 ----------------
__global__ void conv_bf16(const float* __restrict__ in, __hip_bfloat16* __restrict__ out, int n) {
  const int i = (blockIdx.x * 256 + threadIdx.x) * 4;
  if (i >= n) return;
  const float4 v = *(const float4*)(in + i);
  out[i]     = __float2bfloat16(v.x);
  out[i + 1] = __float2bfloat16(v.y);
  out[i + 2] = __float2bfloat16(v.z);
  out[i + 3] = __float2bfloat16(v.w);
}

// ---------------- tiled transpose + convert (fp32 RxC -> bf16 CxR) ----------------
__global__ __launch_bounds__(256) void transpose_conv(const float* __restrict__ in,
                                                      __hip_bfloat16* __restrict__ out,
                                                      int R, int Cc) {
  __shared__ float t[32][33];
  const int nbx = Cc >> 5;
  const int bx = blockIdx.x % nbx, by = blockIdx.x / nbx;
  const int c0 = bx << 5, r0 = by << 5;
  const int tx = threadIdx.x & 31, ty = threadIdx.x >> 5; // ty 0..7
#pragma unroll
  for (int j = 0; j < 32; j += 8)
    t[ty + j][tx] = in[(size_t)(r0 + ty + j) * Cc + c0 + tx];
  __syncthreads();
#pragma unroll
  for (int j = 0; j < 32; j += 8)
    out[(size_t)(c0 + ty + j) * R + r0 + tx] = __float2bfloat16(t[tx][ty + j]);
}

// ---------------- GEMM: C[MxN] = A[MxK] * Bt[NxK]^T  (m97-style 128x128 tile, XCD swizzle) ----------------
template <typename OutT>
__global__ __launch_bounds__(256) void gemm_bt(const __hip_bfloat16* __restrict__ A,
                                               const __hip_bfloat16* __restrict__ Bt,
                                               OutT* __restrict__ C, int M, int N, int K) {
  __shared__ __hip_bfloat16 As[128 * 32];
  __shared__ __hip_bfloat16 Bs[128 * 32];
  const int tid = threadIdx.x;
  const int lane = tid & 63;
  const int wave = tid >> 6;
  const int nTn = N >> 7;
  const int nwg = gridDim.x;
  const int wg = (blockIdx.x & 7) * (nwg >> 3) + (blockIdx.x >> 3);
  const int tm = wg / nTn, tn = wg % nTn;
  const size_t m0 = (size_t)tm * 128, n0 = (size_t)tn * 128;
  const __hip_bfloat16* Ag = A + m0 * K;
  const __hip_bfloat16* Bg = Bt + n0 * K;
  const int wr = wave >> 1, wc = wave & 1;
  const int rsel = lane & 15, k8 = (lane >> 4) << 3;

  f32x4 acc[4][4];
#pragma unroll
  for (int m = 0; m < 4; ++m)
#pragma unroll
    for (int n = 0; n < 4; ++n) acc[m][n] = (f32x4){0.f, 0.f, 0.f, 0.f};

  for (int k0 = 0; k0 < K; k0 += 32) {
    __syncthreads();
#pragma unroll
    for (int i = 0; i < 2; ++i) {
      const int c = i * 256 + tid;
      const int r = c >> 2, kq = (c & 3) << 3;
      gload_lds16(Ag + (size_t)r * K + k0 + kq, &As[(i * 256 + wave * 64) * 8]);
      gload_lds16(Bg + (size_t)r * K + k0 + kq, &Bs[(i * 256 + wave * 64) * 8]);
    }
    __syncthreads();
    bf16x8 af[4], bfr[4];
#pragma unroll
    for (int m = 0; m < 4; ++m)
      af[m] = *(const bf16x8*)&As[(wr * 64 + m * 16 + rsel) * 32 + k8];
#pragma unroll
    for (int n = 0; n < 4; ++n)
      bfr[n] = *(const bf16x8*)&Bs[(wc * 64 + n * 16 + rsel) * 32 + k8];
#pragma unroll
    for (int m = 0; m < 4; ++m)
#pragma unroll
      for (int n = 0; n < 4; ++n)
        acc[m][n] = __builtin_amdgcn_mfma_f32_16x16x32_bf16(af[m], bfr[n], acc[m][n], 0, 0, 0);
  }

  const int rowb = (lane >> 4) << 2;
#pragma unroll
  for (int m = 0; m < 4; ++m)
#pragma unroll
    for (int n = 0; n < 4; ++n) {
      const size_t r0 = m0 + wr * 64 + m * 16 + rowb;
      const size_t cc = n0 + wc * 64 + n * 16 + rsel;
#pragma unroll
      for (int j = 0; j < 4; ++j) {
        const float v = acc[m][n][j];
        if constexpr (sizeof(OutT) == 4)
          C[(r0 + j) * N + cc] = v;
        else
          C[(r0 + j) * N + cc] = __float2bfloat16(v);
      }
    }
}

// ---------------- RoPE + extract Q/K (Q pre-scaled by 0.125*log2e) ----------------
__global__ void rope_extract(const __hip_bfloat16* __restrict__ qkv,
                             __hip_bfloat16* __restrict__ Q,
                             __hip_bfloat16* __restrict__ Kr) {
  const int idx = blockIdx.x * 256 + threadIdx.x;
  const int i = idx & 31;
  const int hs = (idx >> 5) % 40;     // 0..31 = Q heads, 32..39 = K heads
  const int r = idx / (40 * 32);      // b*S + s
  const int srow = r & (CS - 1);
  const int b = r >> 11;
  const float inv = exp2f(-(float)i * (13.287712379549449f / 32.0f)); // 10000^(-i/32)
  const float ang = (float)srow * inv;
  const float sn = sinf(ang), cs = cosf(ang);
  const int col = (hs < CNH) ? hs * CHD + 2 * i : CH + (hs - CNH) * CHD + 2 * i;
  const float t1 = __bfloat162float(qkv[(size_t)r * CTHD + col]);
  const float t2 = __bfloat162float(qkv[(size_t)r * CTHD + col + 1]);
  // Q heads carry the whole softmax input scale: 1/sqrt(64) * log2(e)
  const float scl = (hs < CNH) ? 0.18033688011112042f : 1.0f;
  const float ev = (t1 * cs - t2 * sn) * scl;
  const float ov = (t1 * sn + t2 * cs) * scl;
  __hip_bfloat16* dst;
  if (hs < CNH)
    dst = Q + ((((size_t)b * CNH + hs) * CS + srow) * CHD + 2 * i);
  else
    dst = Kr + ((((size_t)b * CNKV + (hs - CNH)) * CS + srow) * CHD + 2 * i);
  dst[0] = __float2bfloat16(ev);
  dst[1] = __float2bfloat16(ov);
}

// ---------------- V extract + transpose: VT[b][kvh][d][s] ----------------
__global__ __launch_bounds__(256) void v_transpose(const __hip_bfloat16* __restrict__ qkv,
                                                   __hip_bfloat16* __restrict__ VT) {
  __shared__ __hip_bfloat16 t[64][72];
  const int bi = blockIdx.x;
  const int stile = bi & 31;
  const int kvh = (bi >> 5) & 7;
  const int b = bi >> 8;
  const int tx = threadIdx.x & 63;
  const int ty = threadIdx.x >> 6; // 0..3
  const int s0 = stile * 64;
#pragma unroll
  for (int j = 0; j < 16; ++j) {
    const int sl = ty * 16 + j;
    t[sl][tx] = qkv[(size_t)(b * CS + s0 + sl) * CTHD + (CH + CNKV * CHD) + kvh * CHD + tx];
  }
  __syncthreads();
#pragma unroll
  for (int j = 0; j < 16; ++j) {
    const int dl = ty * 16 + j;
    VT[(((size_t)b * CNKV + kvh) * CHD + dl) * CS + s0 + tx] = t[tx][dl];
  }
}

// ---------------- GQA causal flash attention ----------------
// Block = (b, kvh, qw): 4 waves = the 4 q-heads of the GQA group sharing LDS K/V
// tiles (double-buffered, swizzled global_load_lds). Swapped-operand MFMA, scores
// in log2 domain (scale folded into Q), defer-max, and a register P-exchange
// (16 shfl) instead of a P-LDS roundtrip.
__global__ __launch_bounds__(256) void attn_fa(const __hip_bfloat16* __restrict__ Q,
                                               const __hip_bfloat16* __restrict__ Kr,
                                               const __hip_bfloat16* __restrict__ VT,
                                               const int* __restrict__ mask,
                                               __hip_bfloat16* __restrict__ O) {
  __shared__ __hip_bfloat16 Ks[2][64 * 64];
  __shared__ __hip_bfloat16 Vs[2][64 * 64];
  const int kvh = blockIdx.x & 7;          // xcd owns one kv-head
  const int slot = blockIdx.x >> 3;        // 0..255
  const int qw = 127 - (slot >> 1);        // heavy-first
  const int b = slot & 1;
  const int tid = threadIdx.x;
  const int wave = tid >> 6, lane = tid & 63;
  const int h = kvh * 4 + wave;            // this wave's q-head
  const int q0 = qw * 16;
  const int rsel = lane & 15;              // this lane's q-row
  const int hi = lane >> 4;                // 0..3
  const int k8 = hi * 8;
  const int rowb = hi * 4;
  const int qr = q0 + rsel;
  const __hip_bfloat16* Qp = Q + (((size_t)b * CNH + h) * CS + q0) * CHD;
  const __hip_bfloat16* Kp = Kr + ((size_t)b * CNKV + kvh) * CS * CHD;
  const __hip_bfloat16* Vp = VT + ((size_t)b * CNKV + kvh) * CHD * CS;
  const int* mp = mask + b * CS;

  bf16x8 qf[2];
  qf[0] = *(const bf16x8*)(Qp + rsel * CHD + k8);
  qf[1] = *(const bf16x8*)(Qp + rsel * CHD + 32 + k8);

  f32x4 o[4]; // o[nt][j] = O^T[nt*16+rowb+j][qr]
#pragma unroll
  for (int nt = 0; nt < 4; ++nt) o[nt] = (f32x4){0.f, 0.f, 0.f, 0.f};
  float mrun = -3e38f, lrun = 0.f;

  const int nkb = (qw >> 2) + 1;

  auto stage = [&](int buf, int key0) {
#pragma unroll
    for (int half = 0; half < 2; ++half) {
      const int c = half * 256 + tid;      // 16B chunk index 0..511
      const int r = c >> 3;                // row 0..63
      const int swz = ((c & 7) ^ (r & 7)) * 8;
      __hip_bfloat16* kd = &Ks[buf][(half * 256 + wave * 64) * 8];
      __hip_bfloat16* vd = &Vs[buf][(half * 256 + wave * 64) * 8];
      gload_lds16(Kp + (size_t)(key0 + r) * CHD + swz, kd);
      gload_lds16(Vp + (size_t)r * CS + key0 + swz, vd);
    }
  };

  const int srcA = rsel + ((hi & 1) << 5); // exchange sources (see derivation)
  const int srcB = srcA + 16;
  const bool lowkt = hi < 2;

  int mcur = mp[lane], mnext = 0;
  stage(0, 0);
  __syncthreads();

  for (int t = 0; t < nkb; ++t) {
    const int cur = t & 1;
    const int key0 = t * 64;
    const bool last = (t == nkb - 1);
    if (!last) {
      stage(cur ^ 1, key0 + 64);
      mnext = mp[key0 + 64 + lane];
    }
    const unsigned long long kvbits = __ballot(mcur > 0);
    const int sz = rsel & 7;
    bf16x8 kc[8];
#pragma unroll
    for (int kt = 0; kt < 4; ++kt) {
      const int row = (kt * 16 + rsel) * 64;
      kc[kt * 2]     = *(const bf16x8*)&Ks[cur][row + ((hi ^ sz) << 3)];
      kc[kt * 2 + 1] = *(const bf16x8*)&Ks[cur][row + (((hi ^ 4) ^ sz) << 3)];
    }
    // S^T = K * Q^T (already in log2 domain via Q pre-scale)
    f32x4 st[4];
#pragma unroll
    for (int kt = 0; kt < 4; ++kt) {
      f32x4 s = (f32x4){0.f, 0.f, 0.f, 0.f};
      s = __builtin_amdgcn_mfma_f32_16x16x32_bf16(kc[kt * 2], qf[0], s, 0, 0, 0);
      s = __builtin_amdgcn_mfma_f32_16x16x32_bf16(kc[kt * 2 + 1], qf[1], s, 0, 0, 0);
      st[kt] = s;
    }
    // V fragments issued now; consumed after softmax
    bf16x8 vf[8];
#pragma unroll
    for (int nt = 0; nt < 4; ++nt) {
      const int row = (nt * 16 + rsel) * 64;
      vf[nt * 2]     = *(const bf16x8*)&Vs[cur][row + ((hi ^ sz) << 3)];
      vf[nt * 2 + 1] = *(const bf16x8*)&Vs[cur][row + (((hi ^ 4) ^ sz) << 3)];
    }
    if (!(kvbits == ~0ull && !last)) {
#pragma unroll
      for (int kt = 0; kt < 4; ++kt)
#pragma unroll
        for (int j = 0; j < 4; ++j) {
          const int idx = kt * 16 + rowb + j;
          const bool bad = !((kvbits >> idx) & 1ull) || (last && key0 + idx > qr);
          if (bad) st[kt][j] = -1e9f;
        }
    }
    // lane-local max over 16 keys, cross-hi combine via 2 shfl
    float pmax = st[0][0];
#pragma unroll
    for (int kt = 0; kt < 4; ++kt)
#pragma unroll
      for (int j = 0; j < 4; ++j) pmax = fmaxf(pmax, st[kt][j]);
    pmax = fmaxf(pmax, __shfl_xor(pmax, 16));
    pmax = fmaxf(pmax, __shfl_xor(pmax, 32));
    // defer-max: only rescale when the running max grew materially
    if (__any(pmax > mrun + 8.0f)) {
      const float mn = fmaxf(mrun, pmax);
      const float al = exp2f(mrun - mn);
      mrun = mn;
      lrun *= al;
#pragma unroll
      for (int nt = 0; nt < 4; ++nt)
#pragma unroll
        for (int j = 0; j < 4; ++j) o[nt][j] *= al;
    }
    float ps = 0.f;
#pragma unroll
    for (int kt = 0; kt < 4; ++kt)
#pragma unroll
      for (int j = 0; j < 4; ++j) {
        const float p = exp2f(st[kt][j] - mrun);
        st[kt][j] = p;
        ps += p;
      }
    ps += __shfl_xor(ps, 16);
    ps += __shfl_xor(ps, 32);
    lrun += ps;
    // pack P rows to bf16 pairs, then register exchange -> B-fragments
    unsigned wv[4][2];
#pragma unroll
    for (int kt = 0; kt < 4; ++kt) {
      wv[kt][0] = (unsigned)bfbits(st[kt][0]) | ((unsigned)bfbits(st[kt][1]) << 16);
      wv[kt][1] = (unsigned)bfbits(st[kt][2]) | ((unsigned)bfbits(st[kt][3]) << 16);
    }
    const unsigned q00A = (unsigned)__shfl((int)wv[0][0], srcA);
    const unsigned q01A = (unsigned)__shfl((int)wv[0][1], srcA);
    const unsigned q10A = (unsigned)__shfl((int)wv[1][0], srcA);
    const unsigned q11A = (unsigned)__shfl((int)wv[1][1], srcA);
    const unsigned q00B = (unsigned)__shfl((int)wv[0][0], srcB);
    const unsigned q01B = (unsigned)__shfl((int)wv[0][1], srcB);
    const unsigned q10B = (unsigned)__shfl((int)wv[1][0], srcB);
    const unsigned q11B = (unsigned)__shfl((int)wv[1][1], srcB);
    const unsigned r20A = (unsigned)__shfl((int)wv[2][0], srcA);
    const unsigned r21A = (unsigned)__shfl((int)wv[2][1], srcA);
    const unsigned r30A = (unsigned)__shfl((int)wv[3][0], srcA);
    const unsigned r31A = (unsigned)__shfl((int)wv[3][1], srcA);
    const unsigned r20B = (unsigned)__shfl((int)wv[2][0], srcB);
    const unsigned r21B = (unsigned)__shfl((int)wv[2][1], srcB);
    const unsigned r30B = (unsigned)__shfl((int)wv[3][0], srcB);
    const unsigned r31B = (unsigned)__shfl((int)wv[3][1], srcB);
    union {
      unsigned u[4];
      bf16x8 v;
    } ua, ub;
    ua.u[0] = lowkt ? q00A : q10A;
    ua.u[1] = lowkt ? q01A : q11A;
    ua.u[2] = lowkt ? q00B : q10B;
    ua.u[3] = lowkt ? q01B : q11B;
    ub.u[0] = lowkt ? r20A : r30A;
    ub.u[1] = lowkt ? r21A : r31A;
    ub.u[2] = lowkt ? r20B : r30B;
    ub.u[3] = lowkt ? r21B : r31B;
    const bf16x8 pb0 = ua.v;
    const bf16x8 pb1 = ub.v;
    // O^T += V^T * P^T
#pragma unroll
    for (int nt = 0; nt < 4; ++nt) {
      o[nt] = __builtin_amdgcn_mfma_f32_16x16x32_bf16(vf[nt * 2], pb0, o[nt], 0, 0, 0);
      o[nt] = __builtin_amdgcn_mfma_f32_16x16x32_bf16(vf[nt * 2 + 1], pb1, o[nt], 0, 0, 0);
    }
    __syncthreads();
    mcur = mnext;
  }

  const float qm = (mp[qr] > 0) ? 1.0f : 0.0f;
  const float inv = qm / fmaxf(lrun, 1e-20f);
  __hip_bfloat16* Orow = O + (((size_t)b * CS + qr) * CNH + h) * CHD;
#pragma unroll
  for (int nt = 0; nt < 4; ++nt) {
    ushort4 ok;
    ok.x = bfbits(o[nt][0] * inv);
    ok.y = bfbits(o[nt][1] * inv);
    ok.z = bfbits(o[nt][2] * inv);
    ok.w = bfbits(o[nt][3] * inv);
    *(ushort4*)(Orow + nt * 16 + rowb) = ok;
  }
}

extern "C" void kernel_launch(void* const* d_in, const int* in_sizes, int n_in,
                              void* d_out, int out_size, void* d_ws, size_t ws_size,
                              hipStream_t stream) {
  const float* x = (const float*)d_in[0];
  const int* mask = (const int*)d_in[1];
  const float* w_qkv = (const float*)d_in[2];
  const float* w_o = (const float*)d_in[3];
  float* out = (float*)d_out;

  char* ws = (char*)d_ws;
  size_t off = 0;
  auto alloc = [&](size_t bytes) {
    char* p = ws + off;
    off += (bytes + 255) & ~(size_t)255;
    return p;
  };
  const size_t M = (size_t)CB * CS; // 4096
  __hip_bfloat16* x_bf  = (__hip_bfloat16*)alloc(M * CH * 2);
  __hip_bfloat16* wqkvT = (__hip_bfloat16*)alloc((size_t)CTHD * CH * 2);
  __hip_bfloat16* woT   = (__hip_bfloat16*)alloc((size_t)CH * CH * 2);
  __hip_bfloat16* qkv   = (__hip_bfloat16*)alloc(M * CTHD * 2);
  __hip_bfloat16* Qb    = (__hip_bfloat16*)alloc((size_t)CB * CNH * CS * CHD * 2);
  __hip_bfloat16* Kb    = (__hip_bfloat16*)alloc((size_t)CB * CNKV * CS * CHD * 2);
  __hip_bfloat16* VTb   = (__hip_bfloat16*)alloc((size_t)CB * CNKV * CHD * CS * 2);
  __hip_bfloat16* attnb = (__hip_bfloat16*)alloc(M * CH * 2);

  conv_bf16<<<(int)(M * CH / 4 / 256), 256, 0, stream>>>(x, x_bf, (int)(M * CH));
  transpose_conv<<<(CTHD / 32) * (CH / 32), 256, 0, stream>>>(w_qkv, wqkvT, CH, CTHD);
  transpose_conv<<<(CH / 32) * (CH / 32), 256, 0, stream>>>(w_o, woT, CH, CH);
  gemm_bt<__hip_bfloat16><<<(int)(M / 128) * (CTHD / 128), 256, 0, stream>>>(
      x_bf, wqkvT, qkv, (int)M, CTHD, CH);
  rope_extract<<<(int)(M * 40 * 32 / 256), 256, 0, stream>>>(qkv, Qb, Kb);
  v_transpose<<<CB * CNKV * 32, 256, 0, stream>>>(qkv, VTb);
  attn_fa<<<CB * CNKV * 128, 256, 0, stream>>>(Qb, Kb, VTb, mask, attnb);
  gemm_bt<float><<<(int)(M / 128) * (CH / 128), 256, 0, stream>>>(
      attnb, woT, out, (int)M, CH, CH);
}

// Round 8
// 247.018 us; speedup vs baseline: 1.1048x; 1.1048x over previous
//
#include <hip/hip_runtime.h>
#include <hip/hip_bf16.h>
#include <cstdint>
#include <cstddef>

typedef __attribute__((ext_vector_type(8))) short bf16x8;
typedef __attribute__((ext_vector_type(4))) float f32x4;

static constexpr int CB  = 2;
static constexpr int CS  = 2048;
static constexpr int CH  = 2048;
static constexpr int CNH = 32;
static constexpr int CNKV = 8;
static constexpr int CHD = 64;
static constexpr int CTHD = 3072; // (NH + 2*NKV)*HD

__device__ __forceinline__ void gload_lds16(const void* g, void* l) {
  __builtin_amdgcn_global_load_lds(
      (const __attribute__((address_space(1))) unsigned int*)g,
      (__attribute__((address_space(3))) unsigned int*)l, 16, 0, 0);
}

__device__ __forceinline__ unsigned short bfbits(float f) {
  __hip_bfloat16 h = __float2bfloat16(f);
  return *(unsigned short*)&h;
}

// ---------------- elementwise fp32 -> bf16 ----------------
__global__ void conv_bf16(const float* __restrict__ in, __hip_bfloat16* __restrict__ out, int n) {
  const int i = (blockIdx.x * 256 + threadIdx.x) * 4;
  if (i >= n) return;
  const float4 v = *(const float4*)(in + i);
  out[i]     = __float2bfloat16(v.x);
  out[i + 1] = __float2bfloat16(v.y);
  out[i + 2] = __float2bfloat16(v.z);
  out[i + 3] = __float2bfloat16(v.w);
}

// ---------------- tiled transpose + convert (fp32 RxC -> bf16 CxR) ----------------
__global__ __launch_bounds__(256) void transpose_conv(const float* __restrict__ in,
                                                      __hip_bfloat16* __restrict__ out,
                                                      int R, int Cc) {
  __shared__ float t[32][33];
  const int nbx = Cc >> 5;
  const int bx = blockIdx.x % nbx, by = blockIdx.x / nbx;
  const int c0 = bx << 5, r0 = by << 5;
  const int tx = threadIdx.x & 31, ty = threadIdx.x >> 5; // ty 0..7
#pragma unroll
  for (int j = 0; j < 32; j += 8)
    t[ty + j][tx] = in[(size_t)(r0 + ty + j) * Cc + c0 + tx];
  __syncthreads();
#pragma unroll
  for (int j = 0; j < 32; j += 8)
    out[(size_t)(c0 + ty + j) * R + r0 + tx] = __float2bfloat16(t[tx][ty + j]);
}

// ---------------- GEMM: C[MxN] = A[MxK] * Bt[NxK]^T  (m97-style 128x128 tile, XCD swizzle) ----------------
template <typename OutT>
__global__ __launch_bounds__(256) void gemm_bt(const __hip_bfloat16* __restrict__ A,
                                               const __hip_bfloat16* __restrict__ Bt,
                                               OutT* __restrict__ C, int M, int N, int K) {
  __shared__ __hip_bfloat16 As[128 * 32];
  __shared__ __hip_bfloat16 Bs[128 * 32];
  const int tid = threadIdx.x;
  const int lane = tid & 63;
  const int wave = tid >> 6;
  const int nTn = N >> 7;
  const int nwg = gridDim.x;
  const int wg = (blockIdx.x & 7) * (nwg >> 3) + (blockIdx.x >> 3);
  const int tm = wg / nTn, tn = wg % nTn;
  const size_t m0 = (size_t)tm * 128, n0 = (size_t)tn * 128;
  const __hip_bfloat16* Ag = A + m0 * K;
  const __hip_bfloat16* Bg = Bt + n0 * K;
  const int wr = wave >> 1, wc = wave & 1;
  const int rsel = lane & 15, k8 = (lane >> 4) << 3;

  f32x4 acc[4][4];
#pragma unroll
  for (int m = 0; m < 4; ++m)
#pragma unroll
    for (int n = 0; n < 4; ++n) acc[m][n] = (f32x4){0.f, 0.f, 0.f, 0.f};

  for (int k0 = 0; k0 < K; k0 += 32) {
    __syncthreads();
#pragma unroll
    for (int i = 0; i < 2; ++i) {
      const int c = i * 256 + tid;
      const int r = c >> 2, kq = (c & 3) << 3;
      gload_lds16(Ag + (size_t)r * K + k0 + kq, &As[(i * 256 + wave * 64) * 8]);
      gload_lds16(Bg + (size_t)r * K + k0 + kq, &Bs[(i * 256 + wave * 64) * 8]);
    }
    __syncthreads();
    bf16x8 af[4], bfr[4];
#pragma unroll
    for (int m = 0; m < 4; ++m)
      af[m] = *(const bf16x8*)&As[(wr * 64 + m * 16 + rsel) * 32 + k8];
#pragma unroll
    for (int n = 0; n < 4; ++n)
      bfr[n] = *(const bf16x8*)&Bs[(wc * 64 + n * 16 + rsel) * 32 + k8];
#pragma unroll
    for (int m = 0; m < 4; ++m)
#pragma unroll
      for (int n = 0; n < 4; ++n)
        acc[m][n] = __builtin_amdgcn_mfma_f32_16x16x32_bf16(af[m], bfr[n], acc[m][n], 0, 0, 0);
  }

  const int rowb = (lane >> 4) << 2;
#pragma unroll
  for (int m = 0; m < 4; ++m)
#pragma unroll
    for (int n = 0; n < 4; ++n) {
      const size_t r0 = m0 + wr * 64 + m * 16 + rowb;
      const size_t cc = n0 + wc * 64 + n * 16 + rsel;
#pragma unroll
      for (int j = 0; j < 4; ++j) {
        const float v = acc[m][n][j];
        if constexpr (sizeof(OutT) == 4)
          C[(r0 + j) * N + cc] = v;
        else
          C[(r0 + j) * N + cc] = __float2bfloat16(v);
      }
    }
}

// ---------------- RoPE + extract Q/K (Q pre-scaled by 0.125*log2e) ----------------
__global__ void rope_extract(const __hip_bfloat16* __restrict__ qkv,
                             __hip_bfloat16* __restrict__ Q,
                             __hip_bfloat16* __restrict__ Kr) {
  const int idx = blockIdx.x * 256 + threadIdx.x;
  const int i = idx & 31;
  const int hs = (idx >> 5) % 40;     // 0..31 = Q heads, 32..39 = K heads
  const int r = idx / (40 * 32);      // b*S + s
  const int srow = r & (CS - 1);
  const int b = r >> 11;
  const float inv = exp2f(-(float)i * (13.287712379549449f / 32.0f)); // 10000^(-i/32)
  const float ang = (float)srow * inv;
  const float sn = sinf(ang), cs = cosf(ang);
  const int col = (hs < CNH) ? hs * CHD + 2 * i : CH + (hs - CNH) * CHD + 2 * i;
  const float t1 = __bfloat162float(qkv[(size_t)r * CTHD + col]);
  const float t2 = __bfloat162float(qkv[(size_t)r * CTHD + col + 1]);
  // Q heads carry the whole softmax input scale: 1/sqrt(64) * log2(e)
  const float scl = (hs < CNH) ? 0.18033688011112042f : 1.0f;
  const float ev = (t1 * cs - t2 * sn) * scl;
  const float ov = (t1 * sn + t2 * cs) * scl;
  __hip_bfloat16* dst;
  if (hs < CNH)
    dst = Q + ((((size_t)b * CNH + hs) * CS + srow) * CHD + 2 * i);
  else
    dst = Kr + ((((size_t)b * CNKV + (hs - CNH)) * CS + srow) * CHD + 2 * i);
  dst[0] = __float2bfloat16(ev);
  dst[1] = __float2bfloat16(ov);
}

// ---------------- V extract + transpose: VT[b][kvh][d][s] ----------------
__global__ __launch_bounds__(256) void v_transpose(const __hip_bfloat16* __restrict__ qkv,
                                                   __hip_bfloat16* __restrict__ VT) {
  __shared__ __hip_bfloat16 t[64][72];
  const int bi = blockIdx.x;
  const int stile = bi & 31;
  const int kvh = (bi >> 5) & 7;
  const int b = bi >> 8;
  const int tx = threadIdx.x & 63;
  const int ty = threadIdx.x >> 6; // 0..3
  const int s0 = stile * 64;
#pragma unroll
  for (int j = 0; j < 16; ++j) {
    const int sl = ty * 16 + j;
    t[sl][tx] = qkv[(size_t)(b * CS + s0 + sl) * CTHD + (CH + CNKV * CHD) + kvh * CHD + tx];
  }
  __syncthreads();
#pragma unroll
  for (int j = 0; j < 16; ++j) {
    const int dl = ty * 16 + j;
    VT[(((size_t)b * CNKV + kvh) * CHD + dl) * CS + s0 + tx] = t[tx][dl];
  }
}

// ---------------- GQA causal flash attention ----------------
// R5-proven structure: block = (b, kvh, qw), 4 waves = 4 q-heads of the GQA group
// sharing LDS K/V tiles (double-buffered, swizzled global_load_lds). Swapped-operand
// MFMA; lane-local softmax in log2 domain (scale folded into Q); defer-max; P
// roundtrip through the padded (stride-72) wave-private LDS buffer.
__global__ __launch_bounds__(256) void attn_fa(const __hip_bfloat16* __restrict__ Q,
                                               const __hip_bfloat16* __restrict__ Kr,
                                               const __hip_bfloat16* __restrict__ VT,
                                               const int* __restrict__ mask,
                                               __hip_bfloat16* __restrict__ O) {
  __shared__ __hip_bfloat16 Ks[2][64 * 64];
  __shared__ __hip_bfloat16 Vs[2][64 * 64];
  __shared__ __hip_bfloat16 P4[4][16][72];
  const int kvh = blockIdx.x & 7;          // xcd owns one kv-head
  const int slot = blockIdx.x >> 3;        // 0..255
  const int qw = 127 - (slot >> 1);        // heavy-first
  const int b = slot & 1;
  const int tid = threadIdx.x;
  const int wave = tid >> 6, lane = tid & 63;
  const int h = kvh * 4 + wave;            // this wave's q-head
  const int q0 = qw * 16;
  const int rsel = lane & 15;              // this lane's q-row
  const int hi = lane >> 4;                // 0..3
  const int k8 = hi * 8;
  const int rowb = hi * 4;
  const int qr = q0 + rsel;
  const __hip_bfloat16* Qp = Q + (((size_t)b * CNH + h) * CS + q0) * CHD;
  const __hip_bfloat16* Kp = Kr + ((size_t)b * CNKV + kvh) * CS * CHD;
  const __hip_bfloat16* Vp = VT + ((size_t)b * CNKV + kvh) * CHD * CS;
  const int* mp = mask + b * CS;
  __hip_bfloat16(*P)[72] = P4[wave];

  bf16x8 qf[2];
  qf[0] = *(const bf16x8*)(Qp + rsel * CHD + k8);
  qf[1] = *(const bf16x8*)(Qp + rsel * CHD + 32 + k8);

  f32x4 o[4]; // o[nt][j] = O^T[nt*16+rowb+j][qr]
#pragma unroll
  for (int nt = 0; nt < 4; ++nt) o[nt] = (f32x4){0.f, 0.f, 0.f, 0.f};
  float mrun = -3e38f, lrun = 0.f;

  const int nkb = (qw >> 2) + 1;

  auto stage = [&](int buf, int key0) {
#pragma unroll
    for (int half = 0; half < 2; ++half) {
      const int c = half * 256 + tid;      // 16B chunk index 0..511
      const int r = c >> 3;                // row 0..63
      const int swz = ((c & 7) ^ (r & 7)) * 8;
      __hip_bfloat16* kd = &Ks[buf][(half * 256 + wave * 64) * 8];
      __hip_bfloat16* vd = &Vs[buf][(half * 256 + wave * 64) * 8];
      gload_lds16(Kp + (size_t)(key0 + r) * CHD + swz, kd);
      gload_lds16(Vp + (size_t)r * CS + key0 + swz, vd);
    }
  };

  int mcur = mp[lane], mnext = 0;
  stage(0, 0);
  __syncthreads();

  for (int t = 0; t < nkb; ++t) {
    const int cur = t & 1;
    const int key0 = t * 64;
    const bool last = (t == nkb - 1);
    if (!last) {
      stage(cur ^ 1, key0 + 64);
      mnext = mp[key0 + 64 + lane];
    }
    const unsigned long long kvbits = __ballot(mcur > 0);
    const int sz = rsel & 7;
    bf16x8 kc[8];
#pragma unroll
    for (int kt = 0; kt < 4; ++kt) {
      const int row = (kt * 16 + rsel) * 64;
      kc[kt * 2]     = *(const bf16x8*)&Ks[cur][row + ((hi ^ sz) << 3)];
      kc[kt * 2 + 1] = *(const bf16x8*)&Ks[cur][row + (((hi ^ 4) ^ sz) << 3)];
    }
    // S^T = K * Q^T (already in log2 domain via Q pre-scale)
    f32x4 st[4];
#pragma unroll
    for (int kt = 0; kt < 4; ++kt) {
      f32x4 s = (f32x4){0.f, 0.f, 0.f, 0.f};
      s = __builtin_amdgcn_mfma_f32_16x16x32_bf16(kc[kt * 2], qf[0], s, 0, 0, 0);
      s = __builtin_amdgcn_mfma_f32_16x16x32_bf16(kc[kt * 2 + 1], qf[1], s, 0, 0, 0);
      st[kt] = s;
    }
    // V fragments issued now; consumed after softmax
    bf16x8 vf[8];
#pragma unroll
    for (int nt = 0; nt < 4; ++nt) {
      const int row = (nt * 16 + rsel) * 64;
      vf[nt * 2]     = *(const bf16x8*)&Vs[cur][row + ((hi ^ sz) << 3)];
      vf[nt * 2 + 1] = *(const bf16x8*)&Vs[cur][row + (((hi ^ 4) ^ sz) << 3)];
    }
    if (!(kvbits == ~0ull && !last)) {
#pragma unroll
      for (int kt = 0; kt < 4; ++kt)
#pragma unroll
        for (int j = 0; j < 4; ++j) {
          const int idx = kt * 16 + rowb + j;
          const bool bad = !((kvbits >> idx) & 1ull) || (last && key0 + idx > qr);
          if (bad) st[kt][j] = -1e9f;
        }
    }
    // lane-local max over 16 keys, cross-hi combine via 2 shfl
    float pmax = st[0][0];
#pragma unroll
    for (int kt = 0; kt < 4; ++kt)
#pragma unroll
      for (int j = 0; j < 4; ++j) pmax = fmaxf(pmax, st[kt][j]);
    pmax = fmaxf(pmax, __shfl_xor(pmax, 16));
    pmax = fmaxf(pmax, __shfl_xor(pmax, 32));
    // defer-max: only rescale when the running max grew materially
    if (__any(pmax > mrun + 8.0f)) {
      const float mn = fmaxf(mrun, pmax);
      const float al = exp2f(mrun - mn);
      mrun = mn;
      lrun *= al;
#pragma unroll
      for (int nt = 0; nt < 4; ++nt)
#pragma unroll
        for (int j = 0; j < 4; ++j) o[nt][j] *= al;
    }
    float ps = 0.f;
#pragma unroll
    for (int kt = 0; kt < 4; ++kt)
#pragma unroll
      for (int j = 0; j < 4; ++j) {
        const float p = exp2f(st[kt][j] - mrun);
        st[kt][j] = p;
        ps += p;
      }
    ps += __shfl_xor(ps, 16);
    ps += __shfl_xor(ps, 32);
    lrun += ps;
    // P^T -> LDS as P[q][key] (8B packed writes, padded stride), read as B-fragments
#pragma unroll
    for (int kt = 0; kt < 4; ++kt) {
      ushort4 pk;
      pk.x = bfbits(st[kt][0]);
      pk.y = bfbits(st[kt][1]);
      pk.z = bfbits(st[kt][2]);
      pk.w = bfbits(st[kt][3]);
      *(ushort4*)&P[rsel][kt * 16 + rowb] = pk;
    }
    const bf16x8 pb0 = *(const bf16x8*)&P[rsel][k8];
    const bf16x8 pb1 = *(const bf16x8*)&P[rsel][32 + k8];
    // O^T += V^T * P^T
#pragma unroll
    for (int nt = 0; nt < 4; ++nt) {
      o[nt] = __builtin_amdgcn_mfma_f32_16x16x32_bf16(vf[nt * 2], pb0, o[nt], 0, 0, 0);
      o[nt] = __builtin_amdgcn_mfma_f32_16x16x32_bf16(vf[nt * 2 + 1], pb1, o[nt], 0, 0, 0);
    }
    __syncthreads();
    mcur = mnext;
  }

  const float qm = (mp[qr] > 0) ? 1.0f : 0.0f;
  const float inv = qm / fmaxf(lrun, 1e-20f);
  __hip_bfloat16* Orow = O + (((size_t)b * CS + qr) * CNH + h) * CHD;
#pragma unroll
  for (int nt = 0; nt < 4; ++nt) {
    ushort4 ok;
    ok.x = bfbits(o[nt][0] * inv);
    ok.y = bfbits(o[nt][1] * inv);
    ok.z = bfbits(o[nt][2] * inv);
    ok.w = bfbits(o[nt][3] * inv);
    *(ushort4*)(Orow + nt * 16 + rowb) = ok;
  }
}

extern "C" void kernel_launch(void* const* d_in, const int* in_sizes, int n_in,
                              void* d_out, int out_size, void* d_ws, size_t ws_size,
                              hipStream_t stream) {
  const float* x = (const float*)d_in[0];
  const int* mask = (const int*)d_in[1];
  const float* w_qkv = (const float*)d_in[2];
  const float* w_o = (const float*)d_in[3];
  float* out = (float*)d_out;

  char* ws = (char*)d_ws;
  size_t off = 0;
  auto alloc = [&](size_t bytes) {
    char* p = ws + off;
    off += (bytes + 255) & ~(size_t)255;
    return p;
  };
  const size_t M = (size_t)CB * CS; // 4096
  __hip_bfloat16* x_bf  = (__hip_bfloat16*)alloc(M * CH * 2);
  __hip_bfloat16* wqkvT = (__hip_bfloat16*)alloc((size_t)CTHD * CH * 2);
  __hip_bfloat16* woT   = (__hip_bfloat16*)alloc((size_t)CH * CH * 2);
  __hip_bfloat16* qkv   = (__hip_bfloat16*)alloc(M * CTHD * 2);
  __hip_bfloat16* Qb    = (__hip_bfloat16*)alloc((size_t)CB * CNH * CS * CHD * 2);
  __hip_bfloat16* Kb    = (__hip_bfloat16*)alloc((size_t)CB * CNKV * CS * CHD * 2);
  __hip_bfloat16* VTb   = (__hip_bfloat16*)alloc((size_t)CB * CNKV * CHD * CS * 2);
  __hip_bfloat16* attnb = (__hip_bfloat16*)alloc(M * CH * 2);

  conv_bf16<<<(int)(M * CH / 4 / 256), 256, 0, stream>>>(x, x_bf, (int)(M * CH));
  transpose_conv<<<(CTHD / 32) * (CH / 32), 256, 0, stream>>>(w_qkv, wqkvT, CH, CTHD);
  transpose_conv<<<(CH / 32) * (CH / 32), 256, 0, stream>>>(w_o, woT, CH, CH);
  gemm_bt<__hip_bfloat16><<<(int)(M / 128) * (CTHD / 128), 256, 0, stream>>>(
      x_bf, wqkvT, qkv, (int)M, CTHD, CH);
  rope_extract<<<(int)(M * 40 * 32 / 256), 256, 0, stream>>>(qkv, Qb, Kb);
  v_transpose<<<CB * CNKV * 32, 256, 0, stream>>>(qkv, VTb);
  attn_fa<<<CB * CNKV * 128, 256, 0, stream>>>(Qb, Kb, VTb, mask, attnb);
  gemm_bt<float><<<(int)(M / 128) * (CH / 128), 256, 0, stream>>>(
      attnb, woT, out, (int)M, CH, CH);
}